// Round 1
// baseline (931.495 us; speedup 1.0000x reference)
//
#include <hip/hip_runtime.h>
#include <math.h>

// Problem constants: x[B=8, C=256, H=256, W=256] fp32; db8 (16-tap) LL-DWT
// mean -> SE-MLP gate -> rescale. LL mean is linear in x: mean = a^T X a / 135^2
// with a[256] precomputed on host from the filter + symmetric padding.

#define BATCH 8
#define CH    256
#define HW    256
#define BC    (BATCH*CH)            // 2048
#define LL    135                   // (256+15)//2

struct AVec { float a[256]; };

// ---- Kernel 1: s[bc] = sum_{i,j} a[i]*a[j]*x[bc,i,j] -----------------------
// One block per (b,c) slice (256x256 fp32 = 256 KB). 256 threads = 4 waves;
// wave rg streams rows [rg*64, rg*64+64), lanes cover a full 1 KB row as
// contiguous float4 -> perfectly coalesced. a[i] is wave-uniform (scalar load).
__global__ __launch_bounds__(256) void wa_reduce(const float* __restrict__ x,
                                                 float* __restrict__ s, AVec av) {
    const int bc = blockIdx.x;
    const float4* __restrict__ xr = (const float4*)(x + (size_t)bc * (HW * HW));
    const int t  = threadIdx.x;
    const int cg = t & 63;      // column group: columns 4*cg..4*cg+3
    const int rg = t >> 6;      // wave id: rows rg*64..rg*64+63
    float4 acc = make_float4(0.f, 0.f, 0.f, 0.f);
    #pragma unroll 4
    for (int i = rg * 64; i < rg * 64 + 64; ++i) {
        float4 v = xr[(size_t)i * 64 + cg];
        const float ai = av.a[i];
        acc.x = fmaf(ai, v.x, acc.x);
        acc.y = fmaf(ai, v.y, acc.y);
        acc.z = fmaf(ai, v.z, acc.z);
        acc.w = fmaf(ai, v.w, acc.w);
    }
    float partial = acc.x * av.a[4*cg+0] + acc.y * av.a[4*cg+1]
                  + acc.z * av.a[4*cg+2] + acc.w * av.a[4*cg+3];
    #pragma unroll
    for (int off = 32; off > 0; off >>= 1)
        partial += __shfl_down(partial, off, 64);
    __shared__ float wsum[4];
    if (cg == 0) wsum[rg] = partial;
    __syncthreads();
    if (t == 0) s[bc] = wsum[0] + wsum[1] + wsum[2] + wsum[3];
}

// ---- Kernel 2: SE-MLP: y=s/135^2; h=relu(y@W1^T); w=sigmoid(h@W2^T) --------
__global__ __launch_bounds__(256) void wa_mlp(const float* __restrict__ s,
                                              const float* __restrict__ W1,
                                              const float* __restrict__ W2,
                                              float* __restrict__ wout) {
    const int b = blockIdx.x;
    const int c = threadIdx.x;
    __shared__ float y[256];
    __shared__ float h[16];
    y[c] = s[b * 256 + c] * (1.0f / (135.0f * 135.0f));
    __syncthreads();
    if (c < 16) {
        float acc = 0.f;
        for (int k = 0; k < 256; ++k) acc = fmaf(y[k], W1[c * 256 + k], acc);
        h[c] = fmaxf(acc, 0.f);
    }
    __syncthreads();
    float acc = 0.f;
    #pragma unroll
    for (int j = 0; j < 16; ++j) acc = fmaf(h[j], W2[c * 16 + j], acc);
    wout[b * 256 + c] = 1.f / (1.f + expf(-acc));
}

// ---- Kernel 3: out = x * w[bc] ---------------------------------------------
// 16384 float4 per (b,c) -> i>>14 is wave-uniform (scalar load of the gate).
__global__ __launch_bounds__(256) void wa_scale(const float4* __restrict__ x,
                                                const float* __restrict__ w,
                                                float4* __restrict__ out) {
    const size_t i = (size_t)blockIdx.x * 256 + threadIdx.x;
    const float wv = w[i >> 14];
    float4 v = x[i];
    v.x *= wv; v.y *= wv; v.z *= wv; v.w *= wv;
    out[i] = v;
}

extern "C" void kernel_launch(void* const* d_in, const int* in_sizes, int n_in,
                              void* d_out, int out_size, void* d_ws, size_t ws_size,
                              hipStream_t stream) {
    const float* x  = (const float*)d_in[0];   // [8,256,256,256]
    const float* W1 = (const float*)d_in[1];   // [16,256]
    const float* W2 = (const float*)d_in[2];   // [256,16]
    float* out = (float*)d_out;                // [8,256,256,256]

    float* s  = (float*)d_ws;                  // [2048] per-(b,c) bilinear sums
    float* wv = s + BC;                        // [2048] gates

    // Host-side: fold the 135 stride-2 output taps (symmetric padding) into a
    // single per-axis weight vector a[256]. Same values every call -> safe
    // under graph capture (baked into kernel args).
    static const double DB8[16] = {
        -0.00011747678400228192, 0.0006754494059985568, -0.0003917403729959771,
        -0.00487035299301066, 0.008746094047015655, 0.013981027917015516,
        -0.04408825393106472, -0.01736930100202211, 0.128747426620186,
        0.00047248457399797254, -0.2840155429624281, -0.015829105256023893,
        0.5853546836548691, 0.6756307362980128, 0.3128715909144659,
        0.05441584224308161};
    double tmp[256];
    for (int j = 0; j < 256; ++j) tmp[j] = 0.0;
    // y[m] = sum_t filt[15-t] * xe[2m+t]; xe[s] = p[s+1]; p[t] = x[sym(t-15)]
    // => original index i = 2m + t - 14; sym: i<0 -> -1-i, i>=256 -> 511-i.
    for (int m = 0; m < LL; ++m) {
        for (int t = 0; t < 16; ++t) {
            int i = 2 * m + t - 14;
            int j = (i < 0) ? (-1 - i) : ((i >= 256) ? (511 - i) : i);
            tmp[j] += DB8[15 - t];
        }
    }
    AVec av;
    for (int j = 0; j < 256; ++j) av.a[j] = (float)tmp[j];

    wa_reduce<<<BC, 256, 0, stream>>>(x, s, av);
    wa_mlp<<<BATCH, 256, 0, stream>>>(s, W1, W2, wv);
    const int n4 = BATCH * CH * HW * HW / 4;   // 33554432 float4
    wa_scale<<<n4 / 256, 256, 0, stream>>>((const float4*)x, wv, (float4*)out);
}